// Round 1
// baseline (1528.957 us; speedup 1.0000x reference)
//
#include <hip/hip_runtime.h>
#include <cmath>

// xfb: (N=64, B=16, C=22, T=4000) fp32; WT: (B=16, M=16, C=22) fp32
// out[n,b,m] = log(diag / sum_m diag), diag = sum_t (W.x)^2 ; 1/sqrt(T) cancels.
//
// R4 post-mortem: still spilled (WRITE 325 MB = d[16]f4 round-tripped per
// iter). Structural cause: g-outer/m-inner keeps 16 float4 partial-z live
// (64 VGPR) simultaneously with pipelined x loads (88) + acc (16) -> >256.
// R5 fix: invert the nest. Load xv[22] (88 VGPR, read-only) once per j,
// then m-sequential: ONE z float4 live at a time, squared into acc[m]
// immediately. Peak liveness ~130 VGPR. launch_bounds(256,3) caps at ~168
// (no spill headroom needed beyond ~140) -> 12 waves/CU.

#define N_ 64
#define B_ 16
#define C_ 22
#define T_ 4000
#define M_ 16
#define CP_ 24   // padded row stride for W in LDS (16-B aligned rows)

__global__ __launch_bounds__(256, 3)
void OVR_CSP_kernel(const float* __restrict__ xfb,
                    const float* __restrict__ WT,
                    float* __restrict__ out) {
    const int bid = blockIdx.x;        // n*B + b
    const int b   = bid & (B_ - 1);
    const int tid = threadIdx.x;

    __shared__ __align__(16) float wsh[M_ * CP_];  // 16 rows x 24 floats
    __shared__ float red[4][M_];
    __shared__ float dsh[M_];

    for (int i = tid; i < M_ * CP_; i += 256) {
        const int m = i / CP_, c = i - m * CP_;
        wsh[i] = (c < C_) ? WT[b * (M_ * C_) + m * C_ + c] : 0.f;
    }
    __syncthreads();

    // Block-uniform base pointer; per-thread variation via one 32-bit
    // element offset -> saddr-form loads.
    const float* __restrict__ xb = xfb + (size_t)bid * (C_ * T_);

    float acc[M_];
    #pragma unroll
    for (int m = 0; m < M_; ++m) acc[m] = 0.f;

    const int J = T_ / 4;              // 1000 float4 columns
    for (int j = tid; j < J; j += 256) {
        const int off = 4 * j;         // per-thread 32-bit element offset

        // All 22 channels for this 4-column slab, held in registers and
        // reused by all 16 filters. 88 VGPRs, read-only after load.
        float4 xv[C_];
        #pragma unroll
        for (int c = 0; c < C_; ++c)
            xv[c] = *(const float4*)(xb + c * T_ + off);

        // m-sequential: exactly one partial-z float4 live at any time.
        #pragma unroll
        for (int m = 0; m < M_; ++m) {
            const float4 w0 = *(const float4*)&wsh[m * CP_ + 0];
            const float4 w1 = *(const float4*)&wsh[m * CP_ + 4];
            const float4 w2 = *(const float4*)&wsh[m * CP_ + 8];
            const float4 w3 = *(const float4*)&wsh[m * CP_ + 12];
            const float4 w4 = *(const float4*)&wsh[m * CP_ + 16];
            const float2 w5 = *(const float2*)&wsh[m * CP_ + 20];

            float4 z = make_float4(0.f, 0.f, 0.f, 0.f);
            #define ACC4(W, XC)                  \
                z.x = fmaf((W), (XC).x, z.x);    \
                z.y = fmaf((W), (XC).y, z.y);    \
                z.z = fmaf((W), (XC).z, z.z);    \
                z.w = fmaf((W), (XC).w, z.w);
            ACC4(w0.x, xv[0])  ACC4(w0.y, xv[1])  ACC4(w0.z, xv[2])  ACC4(w0.w, xv[3])
            ACC4(w1.x, xv[4])  ACC4(w1.y, xv[5])  ACC4(w1.z, xv[6])  ACC4(w1.w, xv[7])
            ACC4(w2.x, xv[8])  ACC4(w2.y, xv[9])  ACC4(w2.z, xv[10]) ACC4(w2.w, xv[11])
            ACC4(w3.x, xv[12]) ACC4(w3.y, xv[13]) ACC4(w3.z, xv[14]) ACC4(w3.w, xv[15])
            ACC4(w4.x, xv[16]) ACC4(w4.y, xv[17]) ACC4(w4.z, xv[18]) ACC4(w4.w, xv[19])
            ACC4(w5.x, xv[20]) ACC4(w5.y, xv[21])
            #undef ACC4

            acc[m] = fmaf(z.x, z.x, acc[m]);
            acc[m] = fmaf(z.y, z.y, acc[m]);
            acc[m] = fmaf(z.z, z.z, acc[m]);
            acc[m] = fmaf(z.w, z.w, acc[m]);
        }
    }

    // wave reduction (wave = 64)
    #pragma unroll
    for (int m = 0; m < M_; ++m) {
        float v = acc[m];
        #pragma unroll
        for (int off = 32; off > 0; off >>= 1)
            v += __shfl_down(v, off, 64);
        acc[m] = v;
    }

    const int wave = tid >> 6;
    const int lane = tid & 63;
    if (lane == 0) {
        #pragma unroll
        for (int m = 0; m < M_; ++m) red[wave][m] = acc[m];
    }
    __syncthreads();

    if (tid < M_)
        dsh[tid] = red[0][tid] + red[1][tid] + red[2][tid] + red[3][tid];
    __syncthreads();

    if (tid < M_) {
        float total = 0.f;
        #pragma unroll
        for (int m = 0; m < M_; ++m) total += dsh[m];
        out[(size_t)bid * M_ + tid] = logf(dsh[tid] / total);
    }
}

extern "C" void kernel_launch(void* const* d_in, const int* in_sizes, int n_in,
                              void* d_out, int out_size, void* d_ws, size_t ws_size,
                              hipStream_t stream) {
    const float* xfb = (const float*)d_in[0];
    const float* WT  = (const float*)d_in[1];
    float* out = (float*)d_out;

    dim3 grid(N_ * B_);   // 1024 blocks, one per (n,b)
    dim3 block(256);
    OVR_CSP_kernel<<<grid, block, 0, stream>>>(xfb, WT, out);
}

// Round 2
// 1501.107 us; speedup vs baseline: 1.0186x; 1.0186x over previous
//
#include <hip/hip_runtime.h>
#include <cmath>

// xfb: (N=64, B=16, C=22, T=4000) fp32; WT: (B=16, M=16, C=22) fp32
// out[n,b,m] = log(diag / sum_m diag), diag = sum_t (W.x)^2 ; 1/sqrt(T) cancels.
//
// R5 post-mortem: xv[22] float4 (88 VGPR) got SPILLED by the allocator
// (VGPR=84, WRITE 462 MB): full m-unroll + LICM-hoisted w reads + pipelined
// next-iter loads pushed transient pressure past the cap, and the spill
// heuristic picked the long-live-range xv array. Same death as R4's d[16].
// R6: make the per-thread array un-spillably small — SCALAR xv[22] (22 VGPR).
// Non-hoistable liveness ~70 << cap 128 (launch_bounds(256,4)). One t-column
// per thread per iter; 22 coalesced dword loads; w rows via float4 LDS
// broadcast. Memory-bound target: 360 MB -> ~60 us/dispatch.

#define N_ 64
#define B_ 16
#define C_ 22
#define T_ 4000
#define M_ 16
#define CP_ 24   // padded row stride for W in LDS (96-B rows, 16-B aligned)

__global__ __launch_bounds__(256, 4)
void OVR_CSP_kernel(const float* __restrict__ xfb,
                    const float* __restrict__ WT,
                    float* __restrict__ out) {
    const int bid = blockIdx.x;        // n*B + b
    const int b   = bid & (B_ - 1);
    const int tid = threadIdx.x;

    __shared__ __align__(16) float wsh[M_ * CP_];  // 16 rows x 24 floats
    __shared__ float red[4][M_];
    __shared__ float dsh[M_];

    for (int i = tid; i < M_ * CP_; i += 256) {
        const int m = i / CP_, c = i - m * CP_;
        wsh[i] = (c < C_) ? WT[b * (M_ * C_) + m * C_ + c] : 0.f;
    }
    __syncthreads();

    // Block-uniform base pointer; per-thread variation via one 32-bit
    // element offset -> saddr-form loads.
    const float* __restrict__ xb = xfb + (size_t)bid * (C_ * T_);

    float acc[M_];
    #pragma unroll
    for (int m = 0; m < M_; ++m) acc[m] = 0.f;

    // One scalar t-column per thread per iteration. xv[22] scalars = 22 VGPR.
    #pragma unroll 1
    for (int t = tid; t < T_; t += 256) {
        float xv[C_];
        #pragma unroll
        for (int c = 0; c < C_; ++c)
            xv[c] = xb[c * T_ + t];    // coalesced dword loads (256 B/wave)

        #pragma unroll
        for (int m = 0; m < M_; ++m) {
            const float4 w0 = *(const float4*)&wsh[m * CP_ + 0];
            const float4 w1 = *(const float4*)&wsh[m * CP_ + 4];
            const float4 w2 = *(const float4*)&wsh[m * CP_ + 8];
            const float4 w3 = *(const float4*)&wsh[m * CP_ + 12];
            const float4 w4 = *(const float4*)&wsh[m * CP_ + 16];
            const float2 w5 = *(const float2*)&wsh[m * CP_ + 20];

            float z = 0.f;
            z = fmaf(w0.x, xv[0],  z);
            z = fmaf(w0.y, xv[1],  z);
            z = fmaf(w0.z, xv[2],  z);
            z = fmaf(w0.w, xv[3],  z);
            z = fmaf(w1.x, xv[4],  z);
            z = fmaf(w1.y, xv[5],  z);
            z = fmaf(w1.z, xv[6],  z);
            z = fmaf(w1.w, xv[7],  z);
            z = fmaf(w2.x, xv[8],  z);
            z = fmaf(w2.y, xv[9],  z);
            z = fmaf(w2.z, xv[10], z);
            z = fmaf(w2.w, xv[11], z);
            z = fmaf(w3.x, xv[12], z);
            z = fmaf(w3.y, xv[13], z);
            z = fmaf(w3.z, xv[14], z);
            z = fmaf(w3.w, xv[15], z);
            z = fmaf(w4.x, xv[16], z);
            z = fmaf(w4.y, xv[17], z);
            z = fmaf(w4.z, xv[18], z);
            z = fmaf(w4.w, xv[19], z);
            z = fmaf(w5.x, xv[20], z);
            z = fmaf(w5.y, xv[21], z);

            acc[m] = fmaf(z, z, acc[m]);
        }
    }

    // wave reduction (wave = 64)
    #pragma unroll
    for (int m = 0; m < M_; ++m) {
        float v = acc[m];
        #pragma unroll
        for (int off = 32; off > 0; off >>= 1)
            v += __shfl_down(v, off, 64);
        acc[m] = v;
    }

    const int wave = tid >> 6;
    const int lane = tid & 63;
    if (lane == 0) {
        #pragma unroll
        for (int m = 0; m < M_; ++m) red[wave][m] = acc[m];
    }
    __syncthreads();

    if (tid < M_)
        dsh[tid] = red[0][tid] + red[1][tid] + red[2][tid] + red[3][tid];
    __syncthreads();

    if (tid < M_) {
        float total = 0.f;
        #pragma unroll
        for (int m = 0; m < M_; ++m) total += dsh[m];
        out[(size_t)bid * M_ + tid] = logf(dsh[tid] / total);
    }
}

extern "C" void kernel_launch(void* const* d_in, const int* in_sizes, int n_in,
                              void* d_out, int out_size, void* d_ws, size_t ws_size,
                              hipStream_t stream) {
    const float* xfb = (const float*)d_in[0];
    const float* WT  = (const float*)d_in[1];
    float* out = (float*)d_out;

    dim3 grid(N_ * B_);   // 1024 blocks, one per (n,b)
    dim3 block(256);
    OVR_CSP_kernel<<<grid, block, 0, stream>>>(xfb, WT, out);
}

// Round 3
// 506.246 us; speedup vs baseline: 3.0202x; 2.9652x over previous
//
#include <hip/hip_runtime.h>
#include <cmath>

// xfb: (N=64, B=16, C=22, T=4000) fp32; WT: (B=16, M=16, C=22) fp32
// out[n,b,m] = log(diag / sum_m diag), diag = sum_t (W.x)^2 ; 1/sqrt(T) cancels.
//
// R6 post-mortem: empirical rule on this toolchain: VGPR cap = 256/min_waves
// ((256,4)->64, (256,3)->84, (256,1)->256). At cap 64 the xv/acc set spilled
// AND got reloaded per-m: FETCH 2.43 GB (= 360 ideal + ~2.1 GB scratch
// re-reads), WRITE 305 MB. Structural root cause across R4-R6: a thread
// computing all 16 m needs all 352 W scalars -> not hoistable (352 regs),
// and LDS-streaming them is ~96 ds_read_b128/t-iter (~120 us LDS-bound).
// R7: lane-quarter m-specialization. Each 16-lane group owns 4 m's ->
// wreg[4][22]=88 VGPR read-only + xv[22] + acc[4] ~ 125 live << cap 256
// ((256,1)). Zero main-loop LDS, nothing spillable. Cost: 4-way redundant
// x loads (64B/wave/instr, aligned) -> ~22K VMEM instr/CU ~ 37 us issue,
// under the 57 us HBM floor. Memory-bound by construction.

#define N_ 64
#define B_ 16
#define C_ 22
#define T_ 4000
#define M_ 16
#define CP_ 24   // padded row stride for W in LDS

__global__ __launch_bounds__(256, 1)
void OVR_CSP_kernel(const float* __restrict__ xfb,
                    const float* __restrict__ WT,
                    float* __restrict__ out) {
    const int bid  = blockIdx.x;       // n*B + b
    const int b    = bid & (B_ - 1);
    const int tid  = threadIdx.x;
    const int wave = tid >> 6;         // 0..3
    const int lane = tid & 63;
    const int q    = lane >> 4;        // lane-quarter -> m-group 4q..4q+3
    const int sub  = lane & 15;        // column index within group

    __shared__ __align__(16) float wsh[M_ * CP_];
    __shared__ float red[4][M_];
    __shared__ float dsh[M_];

    for (int i = tid; i < M_ * CP_; i += 256) {
        const int m = i / CP_, c = i - m * CP_;
        wsh[i] = (c < C_) ? WT[b * (M_ * C_) + m * C_ + c] : 0.f;
    }
    __syncthreads();

    // Per-thread W registers: the 4 m-rows owned by this lane-quarter.
    // 88 VGPRs, read-only, static-indexed (stays in registers).
    float wreg[4][C_];
    #pragma unroll
    for (int j = 0; j < 4; ++j)
        #pragma unroll
        for (int c = 0; c < C_; ++c)
            wreg[j][c] = wsh[(4 * q + j) * CP_ + c];

    const float* __restrict__ xb = xfb + (size_t)bid * (C_ * T_);

    float acc[4] = {0.f, 0.f, 0.f, 0.f};

    // Per iteration the block covers 64 distinct t-columns:
    // wave w covers columns w*16 + sub (+64 each iter); all 4 lane-quarters
    // process the same 16 columns for their own m-group (4-way broadcast
    // loads, one aligned 64-B request per instruction).
    #pragma unroll 1
    for (int t = wave * 16 + sub; t < T_; t += 64) {
        float xv[C_];
        #pragma unroll
        for (int c = 0; c < C_; ++c)
            xv[c] = xb[c * T_ + t];

        #pragma unroll
        for (int j = 0; j < 4; ++j) {
            float z = 0.f;
            #pragma unroll
            for (int c = 0; c < C_; ++c)
                z = fmaf(wreg[j][c], xv[c], z);
            acc[j] = fmaf(z, z, acc[j]);
        }
    }

    // Reduce over the 16 lanes of each quarter (columns), per m.
    #pragma unroll
    for (int j = 0; j < 4; ++j) {
        float v = acc[j];
        v += __shfl_down(v, 8, 16);
        v += __shfl_down(v, 4, 16);
        v += __shfl_down(v, 2, 16);
        v += __shfl_down(v, 1, 16);
        if (sub == 0) red[wave][4 * q + j] = v;
    }
    __syncthreads();

    if (tid < M_)
        dsh[tid] = red[0][tid] + red[1][tid] + red[2][tid] + red[3][tid];
    __syncthreads();

    if (tid < M_) {
        float total = 0.f;
        #pragma unroll
        for (int m = 0; m < M_; ++m) total += dsh[m];
        out[(size_t)bid * M_ + tid] = logf(dsh[tid] / total);
    }
}

extern "C" void kernel_launch(void* const* d_in, const int* in_sizes, int n_in,
                              void* d_out, int out_size, void* d_ws, size_t ws_size,
                              hipStream_t stream) {
    const float* xfb = (const float*)d_in[0];
    const float* WT  = (const float*)d_in[1];
    float* out = (float*)d_out;

    dim3 grid(N_ * B_);   // 1024 blocks, one per (n,b)
    dim3 block(256);
    OVR_CSP_kernel<<<grid, block, 0, stream>>>(xfb, WT, out);
}

// Round 4
// 501.975 us; speedup vs baseline: 3.0459x; 1.0085x over previous
//
#include <hip/hip_runtime.h>
#include <cmath>

// xfb: (N=64, B=16, C=22, T=4000) fp32; WT: (B=16, M=16, C=22) fp32
// out[n,b,m] = log(diag / sum_m diag), diag = sum_t (W.x)^2 ; 1/sqrt(T) cancels.
//
// R7 post-mortem: spill finally dead (kernel dropped below the 224-us harness
// fills). Remaining cost: lane-quarter m-split made every wave load touch
// only 64 useful bytes (4 quarters read the same 16 dwords) -> 4x VMEM
// instructions, fragmented requests.
// R8: m-split across WAVES instead. Wave w owns m 4w..4w+3, sweeps ALL t
// with t=lane (+64) -> every load is a fully-coalesced 256-B wave request.
// The 4-way x re-read moves to inter-wave reuse of the same 352-KB slab,
// absorbed by L1/L2 (waves run in near-lockstep). No cross-wave reduction:
// each m fully owned by one wave. Liveness: wreg[4][22]=88 + xv[22] + acc[4]
// ~ 125 static << 256 cap at (256,1). VALU ~22 us, HBM floor ~57 us.

#define N_ 64
#define B_ 16
#define C_ 22
#define T_ 4000
#define M_ 16

__global__ __launch_bounds__(256, 1)
void OVR_CSP_kernel(const float* __restrict__ xfb,
                    const float* __restrict__ WT,
                    float* __restrict__ out) {
    const int bid  = blockIdx.x;       // n*B + b
    const int b    = bid & (B_ - 1);
    const int tid  = threadIdx.x;
    const int wave = tid >> 6;         // 0..3  -> owns m = 4*wave..4*wave+3
    const int lane = tid & 63;

    __shared__ float dsh[M_];

    // This wave's 4 W rows, loaded straight from global (wave-uniform
    // broadcast reads, tiny). 88 VGPRs, read-only, static-indexed.
    const float* __restrict__ wb = WT + b * (M_ * C_) + (4 * wave) * C_;
    float wreg[4][C_];
    #pragma unroll
    for (int j = 0; j < 4; ++j)
        #pragma unroll
        for (int c = 0; c < C_; ++c)
            wreg[j][c] = wb[j * C_ + c];

    const float* __restrict__ xb = xfb + (size_t)bid * (C_ * T_);

    float acc[4] = {0.f, 0.f, 0.f, 0.f};

    // Each wave sweeps all 4000 columns; every xv load is a fully-coalesced
    // 256-B request (64 lanes x consecutive dwords).
    #pragma unroll 1
    for (int t = lane; t < T_; t += 64) {
        float xv[C_];
        #pragma unroll
        for (int c = 0; c < C_; ++c)
            xv[c] = xb[c * T_ + t];

        #pragma unroll
        for (int j = 0; j < 4; ++j) {
            float z = 0.f;
            #pragma unroll
            for (int c = 0; c < C_; ++c)
                z = fmaf(wreg[j][c], xv[c], z);
            acc[j] = fmaf(z, z, acc[j]);
        }
    }

    // Full-wave reduction; each m owned by exactly one wave.
    #pragma unroll
    for (int j = 0; j < 4; ++j) {
        float v = acc[j];
        #pragma unroll
        for (int off = 32; off > 0; off >>= 1)
            v += __shfl_down(v, off, 64);
        if (lane == 0) dsh[4 * wave + j] = v;
    }
    __syncthreads();

    if (tid < M_) {
        float total = 0.f;
        #pragma unroll
        for (int m = 0; m < M_; ++m) total += dsh[m];
        out[(size_t)bid * M_ + tid] = logf(dsh[tid] / total);
    }
}

extern "C" void kernel_launch(void* const* d_in, const int* in_sizes, int n_in,
                              void* d_out, int out_size, void* d_ws, size_t ws_size,
                              hipStream_t stream) {
    const float* xfb = (const float*)d_in[0];
    const float* WT  = (const float*)d_in[1];
    float* out = (float*)d_out;

    dim3 grid(N_ * B_);   // 1024 blocks, one per (n,b)
    dim3 block(256);
    OVR_CSP_kernel<<<grid, block, 0, stream>>>(xfb, WT, out);
}